// Round 8
// baseline (197.901 us; speedup 1.0000x reference)
//
#include <hip/hip_runtime.h>

using short8 = __attribute__((ext_vector_type(8))) short;
using f32x4  = __attribute__((ext_vector_type(4))) float;

__device__ inline unsigned short f2bf(float f) {
  unsigned u = __float_as_uint(f);
  u += 0x7fffu + ((u >> 16) & 1u);
  return (unsigned short)(u >> 16);
}
__device__ inline float bf2f(short s) {
  return __uint_as_float(((unsigned)(unsigned short)s) << 16);
}

// barrier that waits LDS only — global loads stay outstanding (pipeline!)
__device__ inline void barrier_lgkm() {
  asm volatile("s_waitcnt lgkmcnt(0)\n\ts_barrier" ::: "memory");
}

// ------- Kernel 0: ALL prep in one launch -------
// bid < 512:            x NCHW fp32 -> xT (hi) + xTlo (residual) NHWC bf16
//                       VECTORIZED: float4 px-reads (4x fewer VMEM than the
//                       old scalar version — it was issue-bound at ~8.4M 4B
//                       loads), packed (lo<<16|hi) uint LDS tile, b128 reads,
//                       short8 (16B) stores covering full 64B lines.
// 512 <= bid < 2816:    conv weights -> wBt2[ks][o(256)][kc(32)]
// bid >= 2816:          offset weights -> wOt/wOtLo[ks][o(32, >=18 zero)][kc(32)]
__global__ __launch_bounds__(256) void prep_all(
    const float* __restrict__ x, const float* __restrict__ cw,
    const float* __restrict__ ow, unsigned short* __restrict__ xT,
    unsigned short* __restrict__ xTlo, unsigned short* __restrict__ wBt2,
    unsigned short* __restrict__ wOt, unsigned short* __restrict__ wOtLo) {
  // [px 64][col 268] uints; col' = c + 4*(c>>6) keeps 16B alignment for b128
  // reads (268, 68, 8 all ≡ 0 mod 4) and ~2-way banks on both phases.
  __shared__ unsigned int T[64 * 268];   // 68,608 B -> 2 blocks/CU
  int bid = blockIdx.x, tid = threadIdx.x;
  if (bid < 512) {
    int y = bid & 63, b = bid >> 6;
    // ---- phase 1: c = tid; 16 x float4 along px; pack hi|lo into LDS ----
    int c = tid;
    const float* xp = x + (((size_t)((b << 8) + c)) << 12) + (y << 6);
    int colp = c + 4 * (c >> 6);
#pragma unroll 4
    for (int p4 = 0; p4 < 16; ++p4) {
      float4 v = *(const float4*)(xp + p4 * 4);
      float vv[4] = {v.x, v.y, v.z, v.w};
#pragma unroll
      for (int i = 0; i < 4; ++i) {
        unsigned short hi = f2bf(vv[i]);
        unsigned short lo = f2bf(vv[i] - bf2f(hi));
        T[(p4 * 4 + i) * 268 + colp] = ((unsigned)lo << 16) | hi;
      }
    }
    __syncthreads();
    // ---- phase 2: px = tid&63, cq = tid>>6; 2 b128 reads -> short8 stores ----
    int px2 = tid & 63, cq = tid >> 6;
    size_t gbase = (((size_t)((b << 12) + (y << 6) + px2)) << 8) + cq * 64;
#pragma unroll 2
    for (int j = 0; j < 8; ++j) {
      const unsigned* tp = T + px2 * 268 + cq * 68 + j * 8;
      uint4 u0 = *(const uint4*)tp;
      uint4 u1 = *(const uint4*)(tp + 4);
      unsigned uu[8] = {u0.x, u0.y, u0.z, u0.w, u1.x, u1.y, u1.z, u1.w};
      short8 hv, lv;
#pragma unroll
      for (int k = 0; k < 8; ++k) {
        hv[k] = (short)(uu[k] & 0xffffu);
        lv[k] = (short)(uu[k] >> 16);
      }
      *(short8*)(xT + gbase + j * 8) = hv;
      *(short8*)(xTlo + gbase + j * 8) = lv;
    }
  } else if (bid < 2816) {
    int e = (bid - 512) * 256 + tid;   // < 589824
    int kc = e & 31, o = (e >> 5) & 255, ks = e >> 13;
    int c = (ks & 7) * 32 + kc, kt = ks >> 3;
    wBt2[e] = f2bf(cw[(size_t)(o * 256 + c) * 9 + kt]);
  } else {
    int e = (bid - 2816) * 256 + tid;   // < 73728
    int kc = e & 31, o = (e >> 5) & 31, ks = e >> 10;
    int c = (ks & 7) * 32 + kc, kt = ks >> 3;
    float v = (o < 18) ? ow[(size_t)(o * 256 + c) * 9 + kt] : 0.f;
    unsigned short hi = f2bf(v);
    wOt[e] = hi;
    wOtLo[e] = f2bf(v - bf2f(hi));
  }
}

// ------- offset-conv helper (B-panel frag load, proven) -------
__device__ inline void loadBOff2(const unsigned short* wOt, const unsigned short* wOtLo,
                                 int ks, int m16, int quad, short8* bh, short8* bl) {
  const unsigned short* bp = wOt + (ks << 10) + m16 * 32 + quad * 8;
  const unsigned short* bq = wOtLo + (ks << 10) + m16 * 32 + quad * 8;
  bh[0] = *(const short8*)bp;  bh[1] = *(const short8*)(bp + 512);
  bl[0] = *(const short8*)bq;  bl[1] = *(const short8*)(bq + 512);
}

// ------- Kernel 1: offset conv — row-staged + high occupancy -------
// grid 2048 = cp(2b) | h(6b) | b(3b)... mapping: b = bid&7, h = (bid>>3)&63,
// cp = bid>>9 (0..3). 1 WAVE per block (conv3's proven occupancy shape),
// 31.7 KB LDS -> 5 blocks/CU. Each block = chunk pair {cp, cp+4}: stages the
// 3 NHWC rows (hi+lo, 64B/lane coalesced — no scattered 9-tap gather, no 3x
// over-read) into a zero-padded [3][66][40] tile, taps = LDS reads at kx
// shifts (conv4's verified addressing), writes ONE of 4 partials to overlay
// channels 100+cp*18.. (conv3's verified epilogue). No inter-block deps.
__global__ __launch_bounds__(64) void offset_conv5(
    const unsigned short* __restrict__ xT, const unsigned short* __restrict__ xTlo,
    const unsigned short* __restrict__ wOt, const unsigned short* __restrict__ wOtLo,
    float* out) {
  __shared__ unsigned short S[15840];   // hi at +0, lo at +7920 (31,680 B)
  int lane = threadIdx.x;
  int bid = blockIdx.x;
  int b = bid & 7, h = (bid >> 3) & 63, cp = bid >> 9;
  int m16 = lane & 15, quad = lane >> 4;

  // zero the pxp-pad rows (pxp = 0 and 65), all ky, both bufs (conv4-proven)
  {
    short8 z = (short8){0, 0, 0, 0, 0, 0, 0, 0};
    if (lane < 48) {
      int j = lane & 3, r = lane >> 2;          // r in 0..11
      int buf = r >= 6; int rr = r - buf * 6; int ky = rr >> 1, pad = rr & 1;
      int pxp = pad ? 65 : 0;
      *(short8*)(S + buf * 7920 + (ky * 66 + pxp) * 40 + j * 8) = z;
    }
  }

  f32x4 acc[4][2];
#pragma unroll
  for (int mt = 0; mt < 4; ++mt)
#pragma unroll
    for (int j = 0; j < 2; ++j) acc[mt][j] = (f32x4){0.f, 0.f, 0.f, 0.f};

  for (int ci = 0; ci < 2; ++ci) {
    int cc = cp + ci * 4;
    // ---- stage 3 rows (hi+lo) for chunk cc: lane = px, 64 B per row ----
#pragma unroll
    for (int ky = 0; ky < 3; ++ky) {
      int y = h + ky - 1;
      unsigned short* dh = S + (ky * 66 + lane + 1) * 40;
      unsigned short* dl = dh + 7920;
      if ((unsigned)y < 64u) {
        size_t base = (((size_t)((b << 12) + (y << 6) + lane)) << 8) + cc * 32;
        const unsigned short* sh_ = xT + base;
        const unsigned short* sl_ = xTlo + base;
#pragma unroll
        for (int j = 0; j < 4; ++j) {
          *(short8*)(dh + j * 8) = *(const short8*)(sh_ + j * 8);
          *(short8*)(dl + j * 8) = *(const short8*)(sl_ + j * 8);
        }
      } else {
        short8 z = (short8){0, 0, 0, 0, 0, 0, 0, 0};
#pragma unroll
        for (int j = 0; j < 4; ++j) {
          *(short8*)(dh + j * 8) = z;
          *(short8*)(dl + j * 8) = z;
        }
      }
    }
    // wave-local LDS: same-wave DS ordering, no barrier needed (proven)
    // ---- 9 taps from LDS at kx shifts ----
    for (int kt = 0; kt < 9; ++kt) {
      int ky = kt / 3, kx = kt - ky * 3;
      short8 bh[2], bl[2];
      loadBOff2(wOt, wOtLo, kt * 8 + cc, m16, quad, bh, bl);
#pragma unroll
      for (int mt = 0; mt < 4; ++mt) {
        const unsigned short* ap = S + (ky * 66 + mt * 16 + m16 + kx) * 40 + quad * 8;
        short8 ah = *(const short8*)ap;
        short8 al = *(const short8*)(ap + 7920);
#pragma unroll
        for (int j = 0; j < 2; ++j) {
          acc[mt][j] = __builtin_amdgcn_mfma_f32_16x16x32_bf16(ah, bh[j], acc[mt][j], 0, 0, 0);
          acc[mt][j] = __builtin_amdgcn_mfma_f32_16x16x32_bf16(al, bh[j], acc[mt][j], 0, 0, 0);
          acc[mt][j] = __builtin_amdgcn_mfma_f32_16x16x32_bf16(ah, bl[j], acc[mt][j], 0, 0, 0);
        }
      }
    }
  }

  // ---- epilogue (conv3-proven): partial cp -> channels 100+cp*18 .. +17 ----
#pragma unroll
  for (int j = 0; j < 2; ++j) {
    int o = j * 16 + m16;
    if (o < 18) {
      float* po = out + (((size_t)((b << 8) + 100 + cp * 18 + o)) << 12) + (h << 6);
#pragma unroll
      for (int mt = 0; mt < 4; ++mt)
#pragma unroll
        for (int rr = 0; rr < 4; ++rr)
          po[mt * 16 + quad * 4 + rr] = acc[mt][j][rr];
    }
  }
}

// ------- deform_main helpers (R0-proven, verbatim) -------
__device__ inline void gather4(const unsigned short* __restrict__ xT,
                               int bbase, int q, int jt,
                               const int2* cif2, const float4* cwf4,
                               int px, short8* g, float4& wq) {
  int cc = jt / 9, kt = jt - cc * 9;
  int2 si = cif2[kt * 64 + px];
  wq = cwf4[kt * 64 + px];
  const unsigned short* base = xT + (size_t)(unsigned)(bbase + cc * 32 + q * 8);
  g[0] = *(const short8*)(base + si.x);
  g[1] = *(const short8*)(base + si.x + 256);
  g[2] = *(const short8*)(base + si.y);
  g[3] = *(const short8*)(base + si.y + 256);
}
__device__ inline void loadB(const unsigned short* __restrict__ wBt2, int wave,
                             int m16, int quad, int jt, short8* bf) {
  int cc = jt / 9, kt = jt - cc * 9;
  int ks = kt * 8 + cc;
  const unsigned short* bp =
      wBt2 + ((size_t)ks << 13) + (wave << 11) + m16 * 32 + quad * 8;
#pragma unroll
  for (int j = 0; j < 4; ++j)
    bf[j] = *(const short8*)(bp + j * 512);
}

// ------- Kernel 2: fused sample + MFMA GEMM — EXACT round-0 structure -------
// (proven ~79 µs / 72 VGPR). Coord phase reads FOUR offset partials
// (8 loads/entry; R0 read 16, R7 read 2 — both passed).
__global__ __launch_bounds__(256, 2) void deform_main(
    const unsigned short* __restrict__ xT, const float* __restrict__ offb,
    const unsigned short* __restrict__ wBt2, float* out) {
  __shared__ float4 smem4[1504];               // 24064 B
  char* smem = (char*)smem4;
  float4* cwf4 = (float4*)smem;                          // 9216 B
  int2*   cif2 = (int2*)(smem + 9216);                   // 4608 B
  unsigned short* At = (unsigned short*)(smem + 13824);  // 2 x [64][40] bf16

  int tid = threadIdx.x, lane = tid & 63, wave = tid >> 6;
  int b = blockIdx.x & 7, h = blockIdx.x >> 3;

  // --- coord precompute; offsets = sum of 4 staged partials + bias ---
  size_t bb = ((size_t)(b << 8)) << 12;
  for (int it = tid; it < 576; it += 256) {
    int k = it >> 6, px = it & 63;
    int ky = k / 3, kx = k - ky * 3;
    int idx = (h << 6) + px;
    float dy = offb[2 * k], dx = offb[2 * k + 1];
#pragma unroll
    for (int g2 = 0; g2 < 4; ++g2) {
      dy += out[bb + (((size_t)(100 + g2 * 18 + 2 * k)) << 12) + idx];
      dx += out[bb + (((size_t)(101 + g2 * 18 + 2 * k)) << 12) + idx];
    }
    float py = (float)(h - 1 + ky) + dy;
    float pxx = (float)(px - 1 + kx) + dx;
    float y0f = floorf(py), x0f = floorf(pxx);
    int y0 = (int)y0f, x0 = (int)x0f;
    float wy1 = py - y0f, wx1 = pxx - x0f;
    int xb; float wxl, wxr;
    if (x0 >= 0 && x0 <= 62)      { xb = x0; wxl = 1.f - wx1; wxr = wx1; }
    else if (x0 == -1)            { xb = 0;  wxl = wx1;       wxr = 0.f; }
    else if (x0 == 63)            { xb = 62; wxl = 0.f;       wxr = 1.f - wx1; }
    else                          { xb = 0;  wxl = 0.f;       wxr = 0.f; }
    float wy0v = ((unsigned)y0 < 64u) ? (1.f - wy1) : 0.f;
    float wy1v = ((unsigned)(y0 + 1) < 64u) ? wy1 : 0.f;
    int yc0 = min(max(y0, 0), 63), yc1 = min(max(y0 + 1, 0), 63);
    cwf4[it] = make_float4(wy0v * wxl, wy0v * wxr, wy1v * wxl, wy1v * wxr);
    cif2[it] = make_int2(((yc0 << 6) + xb) << 8, ((yc1 << 6) + xb) << 8);
  }
  __syncthreads();

  int m16 = lane & 15, quad = lane >> 4;
  int px = wave * 16 + (lane >> 2);
  int q  = lane & 3;
  int bbase = b << 20;
  f32x4 acc[4][4];
#pragma unroll
  for (int i = 0; i < 4; ++i)
#pragma unroll
    for (int j = 0; j < 4; ++j) acc[i][j] = (f32x4){0.f, 0.f, 0.f, 0.f};

  short8 g[4]; float4 wq; short8 bcur[4];
  gather4(xT, bbase, q, 0, cif2, cwf4, px, g, wq);
  loadB(wBt2, wave, m16, quad, 0, bcur);

  for (int it = 0; it < 72; ++it) {
    int buf = it & 1;
    short8 av;
#pragma unroll
    for (int i = 0; i < 8; ++i) {
      float v = wq.x * bf2f(g[0][i]) + wq.y * bf2f(g[1][i]) +
                wq.z * bf2f(g[2][i]) + wq.w * bf2f(g[3][i]);
      av[i] = (short)f2bf(v);
    }
    *(short8*)(At + buf * 2560 + px * 40 + q * 8) = av;
    int jn = (it < 71) ? it + 1 : 71;
    short8 bnext[4], gn[4]; float4 wqn;
    loadB(wBt2, wave, m16, quad, jn, bnext);
    gather4(xT, bbase, q, jn, cif2, cwf4, px, gn, wqn);
    barrier_lgkm();
    short8 af[4];
#pragma unroll
    for (int mt = 0; mt < 4; ++mt)
      af[mt] = *(const short8*)(At + buf * 2560 + (mt * 16 + m16) * 40 + quad * 8);
#pragma unroll
    for (int mt = 0; mt < 4; ++mt)
#pragma unroll
      for (int j = 0; j < 4; ++j)
        acc[mt][j] = __builtin_amdgcn_mfma_f32_16x16x32_bf16(af[mt], bcur[j],
                                                             acc[mt][j], 0, 0, 0);
#pragma unroll
    for (int i = 0; i < 4; ++i) g[i] = gn[i];
    wq = wqn;
#pragma unroll
    for (int j = 0; j < 4; ++j) bcur[j] = bnext[j];
  }

  // ---- epilogue: direct float4 stores from D-fragments ----
  // o = wave*64 + j*16 + m16 ; px = mt*16 + quad*4 + r (r contiguous)
#pragma unroll
  for (int j = 0; j < 4; ++j) {
    int o = wave * 64 + j * 16 + m16;
    float* po = out + (((size_t)((b << 8) + o)) << 12) + (h << 6) + quad * 4;
#pragma unroll
    for (int mt = 0; mt < 4; ++mt) {
      float4 v = make_float4(acc[mt][j][0], acc[mt][j][1], acc[mt][j][2],
                             acc[mt][j][3]);
      *(float4*)(po + mt * 16) = v;
    }
  }
}

extern "C" void kernel_launch(void* const* d_in, const int* in_sizes, int n_in,
                              void* d_out, int out_size, void* d_ws, size_t ws_size,
                              hipStream_t stream) {
  const float* x     = (const float*)d_in[0];
  const float* offw  = (const float*)d_in[1];
  const float* offb  = (const float*)d_in[2];
  const float* convw = (const float*)d_in[3];
  float* out = (float*)d_out;

  char* ws = (char*)d_ws;
  unsigned short* wOt   = (unsigned short*)ws;                // 147,456 B
  unsigned short* wOtLo = (unsigned short*)(ws + 147456);     // 147,456 B
  unsigned short* wBt2  = (unsigned short*)(ws + 294912);     // 1,179,648 B
  unsigned short* xT    = (unsigned short*)(ws + 1474560);    // 16,777,216 B
  unsigned short* xTlo  = (unsigned short*)(ws + 18251776);   // 16,777,216 B (end 35,028,992)

  prep_all<<<3104, 256, 0, stream>>>(x, convw, offw, xT, xTlo, wBt2, wOt, wOtLo);
  offset_conv5<<<2048, 64, 0, stream>>>(xT, xTlo, wOt, wOtLo, out);
  deform_main<<<512, 256, 0, stream>>>(xT, offb, wBt2, out);
}